// Round 14
// baseline (138.614 us; speedup 1.0000x reference)
//
#include <hip/hip_runtime.h>
#include <hip/hip_bf16.h>

#define NB 16
#define NT 2048
#define NDM 1024
#define NDK 128

typedef __bf16 bf16;
typedef bf16 bf16x4 __attribute__((ext_vector_type(4)));
typedef bf16 bf16x8 __attribute__((ext_vector_type(8)));
typedef float f32x4 __attribute__((ext_vector_type(4)));

__device__ inline bf16 to_bf16(float f) {
    __hip_bfloat16 h = __float2bfloat16(f);
    return *reinterpret_cast<bf16*>(&h);
}

// ---------------------------------------------------------------------------
// Kernel 1: W [1024][128] f32  ->  Wt bf16 [3][128][1024]  (transposed, K-major)
// ---------------------------------------------------------------------------
__global__ __launch_bounds__(256) void transpose_w_kernel(
        const float* __restrict__ Wq, const float* __restrict__ Wk,
        const float* __restrict__ Wv, bf16* __restrict__ Wt) {
    int idx = blockIdx.x * 256 + threadIdx.x;
    int w = idx >> 17;
    int r = idx & (NDM * NDK - 1);
    int k = r >> 7;
    int n = r & (NDK - 1);
    const float* W = (w == 0) ? Wq : ((w == 1) ? Wk : Wv);
    Wt[(size_t)w * NDK * NDM + (size_t)n * NDM + k] = to_bf16(W[(size_t)k * NDK + n]);
}

// ---------------------------------------------------------------------------
// Kernel 2: per-plane projection, BM=64 -> grid 1536 = 6 blocks/CU (~75%
// occupancy ceiling). R2-proven simple staging; the ONE variable vs R8 is
// block count (occupancy). 4 waves, each 64x32 out (4m x 2n frags).
// w==2 blocks write V transposed via LDS restage (Tl unioned over As/Bs).
// ---------------------------------------------------------------------------
__global__ __launch_bounds__(256) void proj_kernel(
        const float* __restrict__ x, const bf16* __restrict__ Wt,
        bf16* __restrict__ qkv, bf16* __restrict__ Vt) {
    // As[64][40] (5120B) @0 | Bs[128][40] (10240B) @5120 ; Tl[128][72] (18432B) union
    __shared__ __align__(16) char smem[18432];
    bf16 (*As)[40] = reinterpret_cast<bf16(*)[40]>(smem);
    bf16 (*Bs)[40] = reinterpret_cast<bf16(*)[40]>(smem + 5120);
    bf16 (*Tl)[72] = reinterpret_cast<bf16(*)[72]>(smem);

    const int tid = threadIdx.x;
    const int lane = tid & 63, wave = tid >> 6;
    const int r16 = lane & 15, kg = lane >> 4;
    const int mb = blockIdx.x;          // 0..511 (64-row tile)
    const int w = blockIdx.y;           // plane
    const float* xA = x + (size_t)mb * 64 * NDM;
    const bf16* Bt = Wt + (size_t)w * NDK * NDM;

    // staging coords
    const int a_row = tid >> 2, a_c = (tid & 3) * 8;     // A: 64 rows x 4 chunks(8)
    const int b_row = tid >> 1, b_c = (tid & 1) * 16;    // B: 128 rows x 2 chunks(16)

    f32x4 acc[4][2];
#pragma unroll
    for (int m = 0; m < 4; m++)
#pragma unroll
        for (int n = 0; n < 2; n++) acc[m][n] = (f32x4){0.f, 0.f, 0.f, 0.f};

    for (int k0 = 0; k0 < NDM; k0 += 32) {
        // stage A: 64x32 f32 -> bf16
        {
            const float* p = xA + (size_t)a_row * NDM + k0 + a_c;
            float4 v0 = *reinterpret_cast<const float4*>(p);
            float4 v1 = *reinterpret_cast<const float4*>(p + 4);
            bf16x4 b0 = { to_bf16(v0.x), to_bf16(v0.y), to_bf16(v0.z), to_bf16(v0.w) };
            bf16x4 b1 = { to_bf16(v1.x), to_bf16(v1.y), to_bf16(v1.z), to_bf16(v1.w) };
            *reinterpret_cast<bf16x4*>(&As[a_row][a_c]) = b0;
            *reinterpret_cast<bf16x4*>(&As[a_row][a_c + 4]) = b1;
        }
        // stage B: 128x32 bf16
        {
            const bf16* p = Bt + (size_t)b_row * NDM + k0 + b_c;
            bf16x8 v0 = *reinterpret_cast<const bf16x8*>(p);
            bf16x8 v1 = *reinterpret_cast<const bf16x8*>(p + 8);
            *reinterpret_cast<bf16x8*>(&Bs[b_row][b_c]) = v0;
            *reinterpret_cast<bf16x8*>(&Bs[b_row][b_c + 8]) = v1;
        }
        __syncthreads();
        bf16x8 af[4], bfr[2];
#pragma unroll
        for (int m = 0; m < 4; m++)
            af[m] = *reinterpret_cast<const bf16x8*>(&As[m * 16 + r16][kg * 8]);
#pragma unroll
        for (int n = 0; n < 2; n++)
            bfr[n] = *reinterpret_cast<const bf16x8*>(&Bs[wave * 32 + n * 16 + r16][kg * 8]);
#pragma unroll
        for (int m = 0; m < 4; m++)
#pragma unroll
            for (int n = 0; n < 2; n++)
                acc[m][n] = __builtin_amdgcn_mfma_f32_16x16x32_bf16(af[m], bfr[n], acc[m][n], 0, 0, 0);
        __syncthreads();
    }

    if (w < 2) {
        bf16* outw = qkv + (size_t)w * (size_t)(NB * NT) * NDK;
#pragma unroll
        for (int m = 0; m < 4; m++) {
            int rowb = mb * 64 + m * 16 + kg * 4;
#pragma unroll
            for (int n = 0; n < 2; n++) {
                int col = wave * 32 + n * 16 + r16;
#pragma unroll
                for (int r = 0; r < 4; r++)
                    outw[(size_t)(rowb + r) * NDK + col] = to_bf16(acc[m][n][r]);
            }
        }
    } else {
        // V: restage transposed tile (Tl[d][t]), then coalesced bf16x8 stores
#pragma unroll
        for (int m = 0; m < 4; m++) {
            int tl = m * 16 + kg * 4;
#pragma unroll
            for (int n = 0; n < 2; n++) {
                int d = wave * 32 + n * 16 + r16;
                bf16x4 pv = { to_bf16(acc[m][n][0]), to_bf16(acc[m][n][1]),
                              to_bf16(acc[m][n][2]), to_bf16(acc[m][n][3]) };
                *reinterpret_cast<bf16x4*>(&Tl[d][tl]) = pv;
            }
        }
        __syncthreads();
        const int b = mb >> 5;              // 32 tiles per batch
        const int t0 = (mb & 31) * 64;
        bf16* Vb = Vt + (size_t)b * NDK * NT;
#pragma unroll
        for (int p = 0; p < 4; p++) {
            int idx = p * 256 + tid;        // 1024 chunks: 128 d-rows x 8
            int d = idx >> 3, c = idx & 7;
            *reinterpret_cast<bf16x8*>(&Vb[(size_t)d * NT + t0 + c * 8]) =
                *reinterpret_cast<const bf16x8*>(&Tl[d][c * 8]);
        }
    }
}

// ---------------------------------------------------------------------------
// Kernel 3: causal flash attention (unchanged: swapped-QK^T softmax, dbuf K/V
// LDS, 1 barrier/step, reg-prefetch, XCD-pinned batches).
// ---------------------------------------------------------------------------
__global__ __launch_bounds__(256) void attn_kernel(
        const bf16* __restrict__ Q, const bf16* __restrict__ K,
        const bf16* __restrict__ Vt, float* __restrict__ out) {
    __shared__ bf16 Ks[2][64][128];
    __shared__ bf16 Vs[2][128][64];
    __shared__ bf16 Ps[4][16][72];
    const int tid = threadIdx.x, lane = tid & 63, wave = tid >> 6;
    const int r16 = lane & 15, kg = lane >> 4;

    const int bid = blockIdx.x;
    const int xcd = bid & 7;
    const int j = bid >> 3;
    const int b = xcd * 2 + (j & 1);
    const int qb = (NT / 64 - 1) - (j >> 1);
    const int q0 = qb * 64;
    const size_t baseB = (size_t)b * NT * NDK;
    const size_t baseVt = (size_t)b * NDK * NT;

    const float scale = 0.08838834764831843f;
    bf16x8 qf[4];
    const int qglob = q0 + wave * 16 + r16;
#pragma unroll
    for (int kc = 0; kc < 4; kc++) {
        bf16x8 raw = *reinterpret_cast<const bf16x8*>(&Q[baseB + (size_t)qglob * NDK + kc * 32 + kg * 8]);
#pragma unroll
        for (int jj = 0; jj < 8; jj++) raw[jj] = to_bf16((float)raw[jj] * scale);
        qf[kc] = raw;
    }

    f32x4 o[8];
#pragma unroll
    for (int n = 0; n < 8; n++) o[n] = (f32x4){0.f, 0.f, 0.f, 0.f};
    float mrun = -INFINITY;
    float lrun = 0.f;

    int krow[4], kcol[4], vrow[4], vcol[4];
#pragma unroll
    for (int i = 0; i < 4; i++) {
        int idx = i * 256 + tid;
        krow[i] = idx >> 4; kcol[i] = idx & 15;
        vrow[i] = idx >> 3; vcol[i] = idx & 7;
    }

    const int nsteps = qb + 1;
    bf16x8 kreg[4], vreg[4];
#pragma unroll
    for (int i = 0; i < 4; i++) {
        kreg[i] = *reinterpret_cast<const bf16x8*>(&K[baseB + (size_t)krow[i] * NDK + kcol[i] * 8]);
        vreg[i] = *reinterpret_cast<const bf16x8*>(&Vt[baseVt + (size_t)vrow[i] * NT + vcol[i] * 8]);
    }
#pragma unroll
    for (int i = 0; i < 4; i++) {
        *reinterpret_cast<bf16x8*>(&Ks[0][krow[i]][(kcol[i] ^ (krow[i] & 7)) * 8]) = kreg[i];
        *reinterpret_cast<bf16x8*>(&Vs[0][vrow[i]][(vcol[i] ^ (vrow[i] & 7)) * 8]) = vreg[i];
    }
    if (nsteps > 1) {
#pragma unroll
        for (int i = 0; i < 4; i++) {
            kreg[i] = *reinterpret_cast<const bf16x8*>(&K[baseB + (size_t)(64 + krow[i]) * NDK + kcol[i] * 8]);
            vreg[i] = *reinterpret_cast<const bf16x8*>(&Vt[baseVt + (size_t)vrow[i] * NT + 64 + vcol[i] * 8]);
        }
    }
    __syncthreads();

    for (int s = 0; s < nsteps; s++) {
        const int cur = s & 1;
        const int kv0 = s * 64;

        f32x4 sfr[4];
#pragma unroll
        for (int n = 0; n < 4; n++) sfr[n] = (f32x4){0.f, 0.f, 0.f, 0.f};
#pragma unroll
        for (int n = 0; n < 4; n++) {
            const int krw = n * 16 + r16;
#pragma unroll
            for (int kc = 0; kc < 4; kc++) {
                bf16x8 kf = *reinterpret_cast<const bf16x8*>(&Ks[cur][krw][((kc * 4 + kg) ^ (krw & 7)) * 8]);
                sfr[n] = __builtin_amdgcn_mfma_f32_16x16x32_bf16(kf, qf[kc], sfr[n], 0, 0, 0);
            }
        }

        if (s == nsteps - 1) {
#pragma unroll
            for (int n = 0; n < 4; n++)
#pragma unroll
                for (int r = 0; r < 4; r++)
                    if (kv0 + n * 16 + kg * 4 + r > qglob) sfr[n][r] = -INFINITY;
        }

        float pm = -INFINITY;
#pragma unroll
        for (int n = 0; n < 4; n++) {
            float t0 = fmaxf(fmaxf(sfr[n][0], sfr[n][1]), fmaxf(sfr[n][2], sfr[n][3]));
            pm = fmaxf(pm, t0);
        }
        pm = fmaxf(pm, __shfl_xor(pm, 16, 64));
        pm = fmaxf(pm, __shfl_xor(pm, 32, 64));

        if (__any(pm > mrun)) {
            float mnew = fmaxf(mrun, pm);
            float corr = __expf(mrun - mnew);
            mrun = mnew;
            lrun *= corr;
            float co[4];
#pragma unroll
            for (int r = 0; r < 4; r++) co[r] = __shfl(corr, kg * 4 + r, 64);
#pragma unroll
            for (int n = 0; n < 8; n++)
#pragma unroll
                for (int r = 0; r < 4; r++) o[n][r] *= co[r];
        }

        float ps = 0.f;
#pragma unroll
        for (int n = 0; n < 4; n++) {
            bf16x4 pw;
#pragma unroll
            for (int r = 0; r < 4; r++) {
                float pv = __expf(sfr[n][r] - mrun);
                ps += pv;
                pw[r] = to_bf16(pv);
            }
            *reinterpret_cast<bf16x4*>(&Ps[wave][r16][n * 16 + kg * 4]) = pw;
        }
        ps += __shfl_xor(ps, 16, 64);
        ps += __shfl_xor(ps, 32, 64);
        lrun += ps;

#pragma unroll
        for (int kc2 = 0; kc2 < 2; kc2++) {
            bf16x8 pf = *reinterpret_cast<const bf16x8*>(&Ps[wave][r16][kc2 * 32 + kg * 8]);
#pragma unroll
            for (int n = 0; n < 8; n++) {
                const int vrw = n * 16 + r16;
                bf16x8 vf = *reinterpret_cast<const bf16x8*>(&Vs[cur][vrw][((kc2 * 4 + kg) ^ (vrw & 7)) * 8]);
                o[n] = __builtin_amdgcn_mfma_f32_16x16x32_bf16(pf, vf, o[n], 0, 0, 0);
            }
        }

        if (s + 1 < nsteps) {
#pragma unroll
            for (int i = 0; i < 4; i++) {
                *reinterpret_cast<bf16x8*>(&Ks[1 - cur][krow[i]][(kcol[i] ^ (krow[i] & 7)) * 8]) = kreg[i];
                *reinterpret_cast<bf16x8*>(&Vs[1 - cur][vrow[i]][(vcol[i] ^ (vrow[i] & 7)) * 8]) = vreg[i];
            }
            if (s + 2 < nsteps) {
                const int kv2 = (s + 2) * 64;
#pragma unroll
                for (int i = 0; i < 4; i++) {
                    kreg[i] = *reinterpret_cast<const bf16x8*>(&K[baseB + (size_t)(kv2 + krow[i]) * NDK + kcol[i] * 8]);
                    vreg[i] = *reinterpret_cast<const bf16x8*>(&Vt[baseVt + (size_t)vrow[i] * NT + kv2 + vcol[i] * 8]);
                }
            }
        }
        __syncthreads();
    }

    float linv = 1.0f / lrun;
    float li[4];
#pragma unroll
    for (int r = 0; r < 4; r++) li[r] = __shfl(linv, kg * 4 + r, 64);
#pragma unroll
    for (int n = 0; n < 8; n++)
#pragma unroll
        for (int r = 0; r < 4; r++) {
            int row = q0 + wave * 16 + kg * 4 + r;
            int col = n * 16 + r16;
            out[baseB + (size_t)row * NDK + col] = o[n][r] * li[r];
        }
}

// ---------------------------------------------------------------------------
extern "C" void kernel_launch(void* const* d_in, const int* in_sizes, int n_in,
                              void* d_out, int out_size, void* d_ws, size_t ws_size,
                              hipStream_t stream) {
    const float* x  = (const float*)d_in[0];
    const float* Wq = (const float*)d_in[1];
    const float* Wk = (const float*)d_in[2];
    const float* Wv = (const float*)d_in[3];
    float* out = (float*)d_out;

    char* ws = (char*)d_ws;
    bf16* Wt  = (bf16*)ws;                        // 768 KB
    bf16* qkv = (bf16*)(ws + (1ull << 20));       // Q,K planes: 16 MB
    bf16* Vtg = (bf16*)(ws + (26ull << 20));      // V^T [B][128][T]: 8 MB

    transpose_w_kernel<<<(3 * NDM * NDK) / 256, 256, 0, stream>>>(Wq, Wk, Wv, Wt);

    // per-plane projection, BM=64 -> 1536 blocks (6/CU), V written transposed
    dim3 g1(512, 3);
    proj_kernel<<<g1, 256, 0, stream>>>(x, Wt, qkv, Vtg);

    bf16* Qp = qkv;
    bf16* Kp = qkv + (size_t)(NB * NT) * NDK;

    attn_kernel<<<dim3((NT / 64) * NB), 256, 0, stream>>>(Qp, Kp, Vtg, out);
}

// Round 15
// 110.014 us; speedup vs baseline: 1.2600x; 1.2600x over previous
//
#include <hip/hip_runtime.h>
#include <hip/hip_bf16.h>

#define NB 16
#define NT 2048
#define NDM 1024
#define NDK 128

typedef __bf16 bf16;
typedef bf16 bf16x4 __attribute__((ext_vector_type(4)));
typedef bf16 bf16x8 __attribute__((ext_vector_type(8)));
typedef float f32x4 __attribute__((ext_vector_type(4)));

__device__ inline bf16 to_bf16(float f) {
    __hip_bfloat16 h = __float2bfloat16(f);
    return *reinterpret_cast<bf16*>(&h);
}

__device__ inline void gload_lds16(const void* g, void* l) {
    __builtin_amdgcn_global_load_lds(
        (const __attribute__((address_space(1))) unsigned int*)g,
        (__attribute__((address_space(3))) unsigned int*)l, 16, 0, 0);
}

#define VMCNT(n) asm volatile("s_waitcnt vmcnt(" #n ")" ::: "memory")
#define LGKM0()  asm volatile("s_waitcnt lgkmcnt(0)" ::: "memory")
#define SCHEDB() __builtin_amdgcn_sched_barrier(0)

// ---------------------------------------------------------------------------
// Kernel 1: W [1024][128] f32  ->  Wt bf16 [3][128][1024]  (transposed, K-major)
// ---------------------------------------------------------------------------
__global__ __launch_bounds__(256) void transpose_w_kernel(
        const float* __restrict__ Wq, const float* __restrict__ Wk,
        const float* __restrict__ Wv, bf16* __restrict__ Wt) {
    int idx = blockIdx.x * 256 + threadIdx.x;
    int w = idx >> 17;
    int r = idx & (NDM * NDK - 1);
    int k = r >> 7;
    int n = r & (NDK - 1);
    const float* W = (w == 0) ? Wq : ((w == 1) ? Wk : Wv);
    Wt[(size_t)w * NDK * NDM + (size_t)n * NDM + k] = to_bf16(W[(size_t)k * NDK + n]);
}

// ---------------------------------------------------------------------------
// Kernel 2: per-plane proj, counted-vmcnt single-barrier pipeline.
// grid 768 (4 blocks/CU via 36.9KB LDS). A reg-staged (f32->cvt->bf16
// ds_write, cvt on STAGING path), As[2] padded [128][40] (bank-clean).
// B via global_load_lds dbuf, pre-swizzled source. vmcnt never drains to 0
// in the loop; one s_barrier per K-step. T5 setprio around MFMA cluster.
// w==2 writes V transposed via Tl restage (unioned LDS).
// ---------------------------------------------------------------------------
__global__ __launch_bounds__(256, 4) void proj_kernel(
        const float* __restrict__ x, const bf16* __restrict__ Wt,
        bf16* __restrict__ qkv, bf16* __restrict__ Vt) {
    // As[2]: [128][40] bf16, 10240 B each @0 | Bs[2]: [128][32] bf16, 8192 B each @20480
    // Tl [128][136] (34816 B) unioned for V epilogue.
    __shared__ __align__(16) char smem[36864];
    const int tid = threadIdx.x;
    const int lane = tid & 63, wave = tid >> 6;
    const int wr = wave >> 1, wc = wave & 1;
    const int r16 = lane & 15, kg = lane >> 4;
    const int mb = blockIdx.x;
    const int w = blockIdx.y;
    const float* xA = x + (size_t)mb * 128 * NDM;
    const bf16* Bt = Wt + (size_t)w * NDK * NDM;

    auto AS = [&](int b) -> bf16* { return (bf16*)(smem + b * 10240); };   // stride 40
    auto BS = [&](int b) -> bf16* { return (bf16*)(smem + 20480 + b * 8192); };  // stride 32

    // A staging: thread -> row (tid>>1), 16 cols at cb=(tid&1)*16
    const int a_row = tid >> 1;
    const int a_cb = (tid & 1) * 16;
    float4 araw[4];
    auto loadA = [&](int kt) {     // 4 vmem
        const float* p = xA + (size_t)a_row * NDM + kt * 32 + a_cb;
#pragma unroll
        for (int i = 0; i < 4; i++) araw[i] = *reinterpret_cast<const float4*>(p + i * 4);
    };
    auto writeA = [&](int buf) {   // 2 ds_write_b128
        bf16* dst = AS(buf) + a_row * 40 + a_cb;
#pragma unroll
        for (int h = 0; h < 2; h++) {
            const float4 lo = araw[2 * h], hi = araw[2 * h + 1];
            bf16x8 v;
            v[0] = to_bf16(lo.x); v[1] = to_bf16(lo.y); v[2] = to_bf16(lo.z); v[3] = to_bf16(lo.w);
            v[4] = to_bf16(hi.x); v[5] = to_bf16(hi.y); v[6] = to_bf16(hi.z); v[7] = to_bf16(hi.w);
            *reinterpret_cast<bf16x8*>(dst + h * 8) = v;
        }
    };
    // B staging: 512 chunks (128 rows x 4), 2 gload_lds/thread, src pre-swizzled
    auto stageB = [&](int buf, int kt) {
#pragma unroll
        for (int p = 0; p < 2; p++) {
            int cid = p * 256 + tid;          // == (p*4+wave)*64 + lane
            int row = cid >> 2, c = cid & 3;
            int cs = c ^ (row & 3);
            gload_lds16(Bt + (size_t)row * NDM + kt * 32 + cs * 8,
                        BS(buf) + (size_t)(p * 256 + wave * 64) * 8);
        }
    };

    f32x4 acc[4][4];
#pragma unroll
    for (int m = 0; m < 4; m++)
#pragma unroll
        for (int n = 0; n < 4; n++) acc[m][n] = (f32x4){0.f, 0.f, 0.f, 0.f};

    // ---- prologue ----
    loadA(0); SCHEDB();            // A0(4)
    stageB(0, 0); SCHEDB();        // +B0(2) = 6
    VMCNT(2);                      // A0 landed; B0 flying
    writeA(0);
    loadA(1); SCHEDB();            // queue [B0(2), A1(4)]
    VMCNT(4);                      // B0 landed; A1 flying
    LGKM0();
    __builtin_amdgcn_s_barrier();  // buf0 valid
    SCHEDB();
    stageB(1, 1); SCHEDB();        // queue [A1(4), B1(2)]

    for (int kt = 0; kt < 32; kt++) {
        const int cur = kt & 1;
        // ---- compute buf[cur]: 8 ds_read_b128 + 16 MFMA ----
        bf16x8 af[4], bfr[4];
#pragma unroll
        for (int m = 0; m < 4; m++)
            af[m] = *reinterpret_cast<const bf16x8*>(AS(cur) + (wr * 64 + m * 16 + r16) * 40 + kg * 8);
#pragma unroll
        for (int n = 0; n < 4; n++) {
            int br = wc * 64 + n * 16 + r16;
            bfr[n] = *reinterpret_cast<const bf16x8*>(BS(cur) + br * 32 + ((kg ^ (br & 3)) * 8));
        }
        __builtin_amdgcn_s_setprio(1);
#pragma unroll
        for (int m = 0; m < 4; m++)
#pragma unroll
            for (int n = 0; n < 4; n++)
                acc[m][n] = __builtin_amdgcn_mfma_f32_16x16x32_bf16(af[m], bfr[n], acc[m][n], 0, 0, 0);
        __builtin_amdgcn_s_setprio(0);

        if (kt + 1 < 32) {
            SCHEDB();
            VMCNT(2);                           // A(t+1) landed; B(t+1)(2) flying
            writeA(1 - cur);                    // cvt+ds_write on staging path
            if (kt + 2 < 32) {
                loadA(kt + 2); SCHEDB();        // queue [B(t+1)2, A(t+2)4]
                VMCNT(4);                       // B(t+1) landed; A(t+2) flying
            } else {
                VMCNT(0);                       // drain B(31)
            }
            LGKM0();                            // my ds_writes visible
            __builtin_amdgcn_s_barrier();       // buf[cur] reads done block-wide
            SCHEDB();
            if (kt + 2 < 32) { stageB(cur, kt + 2); SCHEDB(); }
        }
    }

    // ---- epilogue ----
    __syncthreads();
    if (w < 2) {
        bf16* outw = qkv + (size_t)w * (size_t)(NB * NT) * NDK;
#pragma unroll
        for (int m = 0; m < 4; m++) {
            int rowb = mb * 128 + wr * 64 + m * 16 + kg * 4;
#pragma unroll
            for (int n = 0; n < 4; n++) {
                int col = wc * 64 + n * 16 + r16;
#pragma unroll
                for (int r = 0; r < 4; r++)
                    outw[(size_t)(rowb + r) * NDK + col] = to_bf16(acc[m][n][r]);
            }
        }
    } else {
        bf16 (*Tl)[136] = reinterpret_cast<bf16(*)[136]>(smem);
#pragma unroll
        for (int m = 0; m < 4; m++) {
            int tl = wr * 64 + m * 16 + kg * 4;
#pragma unroll
            for (int n = 0; n < 4; n++) {
                int d = wc * 64 + n * 16 + r16;
                bf16x4 pv = { to_bf16(acc[m][n][0]), to_bf16(acc[m][n][1]),
                              to_bf16(acc[m][n][2]), to_bf16(acc[m][n][3]) };
                *reinterpret_cast<bf16x4*>(&Tl[d][tl]) = pv;
            }
        }
        __syncthreads();
        const int b = mb >> 4;
        const int t0 = (mb & 15) * 128;
        bf16* Vb = Vt + (size_t)b * NDK * NT;
#pragma unroll
        for (int p = 0; p < 8; p++) {
            int idx = p * 256 + tid;          // 2048 chunks: 128 d-rows x 16
            int d = idx >> 4, c = idx & 15;
            *reinterpret_cast<bf16x8*>(&Vb[(size_t)d * NT + t0 + c * 8]) =
                *reinterpret_cast<const bf16x8*>(&Tl[d][c * 8]);
        }
    }
}

// ---------------------------------------------------------------------------
// Kernel 3: causal flash attention (unchanged: swapped-QK^T softmax, dbuf K/V
// LDS, 1 barrier/step, reg-prefetch, XCD-pinned batches).
// ---------------------------------------------------------------------------
__global__ __launch_bounds__(256) void attn_kernel(
        const bf16* __restrict__ Q, const bf16* __restrict__ K,
        const bf16* __restrict__ Vt, float* __restrict__ out) {
    __shared__ bf16 Ks[2][64][128];
    __shared__ bf16 Vs[2][128][64];
    __shared__ bf16 Ps[4][16][72];
    const int tid = threadIdx.x, lane = tid & 63, wave = tid >> 6;
    const int r16 = lane & 15, kg = lane >> 4;

    const int bid = blockIdx.x;
    const int xcd = bid & 7;
    const int j = bid >> 3;
    const int b = xcd * 2 + (j & 1);
    const int qb = (NT / 64 - 1) - (j >> 1);
    const int q0 = qb * 64;
    const size_t baseB = (size_t)b * NT * NDK;
    const size_t baseVt = (size_t)b * NDK * NT;

    const float scale = 0.08838834764831843f;
    bf16x8 qf[4];
    const int qglob = q0 + wave * 16 + r16;
#pragma unroll
    for (int kc = 0; kc < 4; kc++) {
        bf16x8 raw = *reinterpret_cast<const bf16x8*>(&Q[baseB + (size_t)qglob * NDK + kc * 32 + kg * 8]);
#pragma unroll
        for (int jj = 0; jj < 8; jj++) raw[jj] = to_bf16((float)raw[jj] * scale);
        qf[kc] = raw;
    }

    f32x4 o[8];
#pragma unroll
    for (int n = 0; n < 8; n++) o[n] = (f32x4){0.f, 0.f, 0.f, 0.f};
    float mrun = -INFINITY;
    float lrun = 0.f;

    int krow[4], kcol[4], vrow[4], vcol[4];
#pragma unroll
    for (int i = 0; i < 4; i++) {
        int idx = i * 256 + tid;
        krow[i] = idx >> 4; kcol[i] = idx & 15;
        vrow[i] = idx >> 3; vcol[i] = idx & 7;
    }

    const int nsteps = qb + 1;
    bf16x8 kreg[4], vreg[4];
#pragma unroll
    for (int i = 0; i < 4; i++) {
        kreg[i] = *reinterpret_cast<const bf16x8*>(&K[baseB + (size_t)krow[i] * NDK + kcol[i] * 8]);
        vreg[i] = *reinterpret_cast<const bf16x8*>(&Vt[baseVt + (size_t)vrow[i] * NT + vcol[i] * 8]);
    }
#pragma unroll
    for (int i = 0; i < 4; i++) {
        *reinterpret_cast<bf16x8*>(&Ks[0][krow[i]][(kcol[i] ^ (krow[i] & 7)) * 8]) = kreg[i];
        *reinterpret_cast<bf16x8*>(&Vs[0][vrow[i]][(vcol[i] ^ (vrow[i] & 7)) * 8]) = vreg[i];
    }
    if (nsteps > 1) {
#pragma unroll
        for (int i = 0; i < 4; i++) {
            kreg[i] = *reinterpret_cast<const bf16x8*>(&K[baseB + (size_t)(64 + krow[i]) * NDK + kcol[i] * 8]);
            vreg[i] = *reinterpret_cast<const bf16x8*>(&Vt[baseVt + (size_t)vrow[i] * NT + 64 + vcol[i] * 8]);
        }
    }
    __syncthreads();

    for (int s = 0; s < nsteps; s++) {
        const int cur = s & 1;
        const int kv0 = s * 64;

        f32x4 sfr[4];
#pragma unroll
        for (int n = 0; n < 4; n++) sfr[n] = (f32x4){0.f, 0.f, 0.f, 0.f};
#pragma unroll
        for (int n = 0; n < 4; n++) {
            const int krw = n * 16 + r16;
#pragma unroll
            for (int kc = 0; kc < 4; kc++) {
                bf16x8 kf = *reinterpret_cast<const bf16x8*>(&Ks[cur][krw][((kc * 4 + kg) ^ (krw & 7)) * 8]);
                sfr[n] = __builtin_amdgcn_mfma_f32_16x16x32_bf16(kf, qf[kc], sfr[n], 0, 0, 0);
            }
        }

        if (s == nsteps - 1) {
#pragma unroll
            for (int n = 0; n < 4; n++)
#pragma unroll
                for (int r = 0; r < 4; r++)
                    if (kv0 + n * 16 + kg * 4 + r > qglob) sfr[n][r] = -INFINITY;
        }

        float pm = -INFINITY;
#pragma unroll
        for (int n = 0; n < 4; n++) {
            float t0 = fmaxf(fmaxf(sfr[n][0], sfr[n][1]), fmaxf(sfr[n][2], sfr[n][3]));
            pm = fmaxf(pm, t0);
        }
        pm = fmaxf(pm, __shfl_xor(pm, 16, 64));
        pm = fmaxf(pm, __shfl_xor(pm, 32, 64));

        if (__any(pm > mrun)) {
            float mnew = fmaxf(mrun, pm);
            float corr = __expf(mrun - mnew);
            mrun = mnew;
            lrun *= corr;
            float co[4];
#pragma unroll
            for (int r = 0; r < 4; r++) co[r] = __shfl(corr, kg * 4 + r, 64);
#pragma unroll
            for (int n = 0; n < 8; n++)
#pragma unroll
                for (int r = 0; r < 4; r++) o[n][r] *= co[r];
        }

        float ps = 0.f;
#pragma unroll
        for (int n = 0; n < 4; n++) {
            bf16x4 pw;
#pragma unroll
            for (int r = 0; r < 4; r++) {
                float pv = __expf(sfr[n][r] - mrun);
                ps += pv;
                pw[r] = to_bf16(pv);
            }
            *reinterpret_cast<bf16x4*>(&Ps[wave][r16][n * 16 + kg * 4]) = pw;
        }
        ps += __shfl_xor(ps, 16, 64);
        ps += __shfl_xor(ps, 32, 64);
        lrun += ps;

#pragma unroll
        for (int kc2 = 0; kc2 < 2; kc2++) {
            bf16x8 pf = *reinterpret_cast<const bf16x8*>(&Ps[wave][r16][kc2 * 32 + kg * 8]);
#pragma unroll
            for (int n = 0; n < 8; n++) {
                const int vrw = n * 16 + r16;
                bf16x8 vf = *reinterpret_cast<const bf16x8*>(&Vs[cur][vrw][((kc2 * 4 + kg) ^ (vrw & 7)) * 8]);
                o[n] = __builtin_amdgcn_mfma_f32_16x16x32_bf16(pf, vf, o[n], 0, 0, 0);
            }
        }

        if (s + 1 < nsteps) {
#pragma unroll
            for (int i = 0; i < 4; i++) {
                *reinterpret_cast<bf16x8*>(&Ks[1 - cur][krow[i]][(kcol[i] ^ (krow[i] & 7)) * 8]) = kreg[i];
                *reinterpret_cast<bf16x8*>(&Vs[1 - cur][vrow[i]][(vcol[i] ^ (vrow[i] & 7)) * 8]) = vreg[i];
            }
            if (s + 2 < nsteps) {
                const int kv2 = (s + 2) * 64;
#pragma unroll
                for (int i = 0; i < 4; i++) {
                    kreg[i] = *reinterpret_cast<const bf16x8*>(&K[baseB + (size_t)(kv2 + krow[i]) * NDK + kcol[i] * 8]);
                    vreg[i] = *reinterpret_cast<const bf16x8*>(&Vt[baseVt + (size_t)vrow[i] * NT + kv2 + vcol[i] * 8]);
                }
            }
        }
        __syncthreads();
    }

    float linv = 1.0f / lrun;
    float li[4];
#pragma unroll
    for (int r = 0; r < 4; r++) li[r] = __shfl(linv, kg * 4 + r, 64);
#pragma unroll
    for (int n = 0; n < 8; n++)
#pragma unroll
        for (int r = 0; r < 4; r++) {
            int row = q0 + wave * 16 + kg * 4 + r;
            int col = n * 16 + r16;
            out[baseB + (size_t)row * NDK + col] = o[n][r] * li[r];
        }
}

// ---------------------------------------------------------------------------
extern "C" void kernel_launch(void* const* d_in, const int* in_sizes, int n_in,
                              void* d_out, int out_size, void* d_ws, size_t ws_size,
                              hipStream_t stream) {
    const float* x  = (const float*)d_in[0];
    const float* Wq = (const float*)d_in[1];
    const float* Wk = (const float*)d_in[2];
    const float* Wv = (const float*)d_in[3];
    float* out = (float*)d_out;

    char* ws = (char*)d_ws;
    bf16* Wt  = (bf16*)ws;                        // 768 KB
    bf16* qkv = (bf16*)(ws + (1ull << 20));       // Q,K planes: 16 MB
    bf16* Vtg = (bf16*)(ws + (26ull << 20));      // V^T [B][128][T]: 8 MB

    transpose_w_kernel<<<(3 * NDM * NDK) / 256, 256, 0, stream>>>(Wq, Wk, Wv, Wt);

    // per-plane proj, counted-vmcnt single-barrier pipeline, 4 blocks/CU
    dim3 g1(256, 3);
    proj_kernel<<<g1, 256, 0, stream>>>(x, Wt, qkv, Vtg);

    bf16* Qp = qkv;
    bf16* Kp = qkv + (size_t)(NB * NT) * NDK;

    attn_kernel<<<dim3((NT / 64) * NB), 256, 0, stream>>>(Qp, Kp, Vtg, out);
}